// Round 4
// baseline (439.155 us; speedup 1.0000x reference)
//
#include <hip/hip_runtime.h>

#pragma clang fp contract(off)

#define NBOX 4096
#define MBOX 256
#define NBATCH 32
#define GEPS 1e-7f
#define MT 1024
#define MW 16
#define ISLICES 16
#define ROUND_CAP 768

typedef unsigned long long u64;
typedef unsigned int u32;
typedef unsigned short u16;

// ws layout (bytes)
#define WS_ROWCOL 0                                  // u16[32][4096]   = 256 KB
#define WS_TOP8   (NBATCH * NBOX * 2)                // u64[32][256][8] = 512 KB
#define WS_NEGP   (WS_TOP8 + NBATCH * MBOX * 8 * 8)  // f32[32][16]
#define WS_PART   (WS_NEGP + NBATCH * ISLICES * 4)   // f32[32]

__device__ __forceinline__ u64 shflxor_u64(u64 x, int m) {
  u32 lo = (u32)x, hi = (u32)(x >> 32);
  lo = __shfl_xor(lo, m, 64);
  hi = __shfl_xor(hi, m, 64);
  return ((u64)hi << 32) | (u64)lo;
}

// exact IEEE, contract off -> bitwise identical everywhere it's computed
__device__ __forceinline__ u32 iou_bits(float4 a, float areaA, float4 g, float gar) {
  #pragma clang fp contract(off)
  float w = fminf(a.z, g.z) - fmaxf(a.x, g.x);
  float h = fminf(a.w, g.w) - fmaxf(a.y, g.y);
  w = fmaxf(w, 0.0f);
  h = fmaxf(h, 0.0f);
  float inter = w * h;
  float uni = (areaA + gar) - inter;
  float v = inter / uni;  // IoU >= 0: float bits order-preserving
  return __float_as_uint(v);
}

__device__ __forceinline__ float giou_loss(float ax1, float ay1, float ax2, float ay2,
                                           float bx1, float by1, float bx2, float by2) {
  #pragma clang fp contract(off)
  float xi1 = fmaxf(ax1, bx1), yi1 = fmaxf(ay1, by1);
  float xi2 = fminf(ax2, bx2), yi2 = fminf(ay2, by2);
  float inter = fmaxf(xi2 - xi1, 0.0f) * fmaxf(yi2 - yi1, 0.0f);
  float area1 = (ax2 - ax1) * (ay2 - ay1);
  float area2 = (bx2 - bx1) * (by2 - by1);
  float uni = (area1 + area2) - inter;
  float iou = inter / (uni + GEPS);
  float xc1 = fminf(ax1, bx1), yc1 = fminf(ay1, by1);
  float xc2 = fmaxf(ax2, bx2), yc2 = fmaxf(ay2, by2);
  float areac = (xc2 - xc1) * (yc2 - yc1);
  float giou = iou - (areac - uni) / (areac + GEPS);
  return 1.0f - giou;
}

// row key: (iou<<9)|(256-c)  -> max == (val desc, col asc)
// col key: (iou<<13)|(4096-r)-> max == (val desc, row asc)

__global__ __launch_bounds__(1024) void init_rows(
    const float4* __restrict__ pr, const float4* __restrict__ gt,
    u16* __restrict__ rowcolG, float* __restrict__ negpart) {
  __shared__ float4 g[MBOX];
  __shared__ float garea[MBOX];
  __shared__ float red[16];
  const int blk = blockIdx.x;
  const int b = blk >> 4, s = blk & 15;
  const int tid = threadIdx.x, lane = tid & 63, wid = tid >> 6;
  const float4* prb = pr + (size_t)b * NBOX;
  if (tid < MBOX) {
    float4 gg = gt[(size_t)b * MBOX + tid];
    g[tid] = gg;
    garea[tid] = (gg.z - gg.x) * (gg.w - gg.y);
  }
  __syncthreads();
  const int rr = tid >> 2, quad = tid & 3;
  const int r = s * 256 + rr;
  float4 a = prb[r];
  float areaA = (a.z - a.x) * (a.w - a.y);
  u64 best = 0ull;
  for (int k = 0; k < 64; ++k) {
    int c = quad * 64 + k;
    u64 p = ((u64)iou_bits(a, areaA, g[c], garea[c]) << 9) | (u64)(MBOX - c);
    if (p > best) best = p;
  }
  #pragma unroll
  for (int o = 1; o < 4; o <<= 1) {
    u64 q = shflxor_u64(best, o);
    if (q > best) best = q;
  }
  float nd = 0.0f;
  if (quad == 0) {
    rowcolG[(size_t)b * NBOX + r] = (u16)(MBOX - (int)(best & 0x1FFull));
    nd = giou_loss(a.x, a.y, a.z, a.w, 0.0f, 0.0f, 0.0f, 0.0f);
  }
  #pragma unroll
  for (int o = 32; o; o >>= 1) nd += __shfl_xor(nd, o, 64);
  if (lane == 0) red[wid] = nd;
  __syncthreads();
  if (tid == 0) {
    float t = 0.0f;
    for (int w = 0; w < 16; ++w) t += red[w];
    negpart[blk] = t;
  }
}

// one wave per col: lane-local top-8 insertion over 64 rows, then 8x wave-max extraction
__global__ __launch_bounds__(256) void init_cols(
    const float4* __restrict__ pr, const float4* __restrict__ gt,
    u64* __restrict__ top8G) {
  const int blk = blockIdx.x;
  const int b = blk >> 6, cg = blk & 63;
  const int tid = threadIdx.x, lane = tid & 63, wid = tid >> 6;
  const int j = cg * 4 + wid;
  const float4* prb = pr + (size_t)b * NBOX;
  float4 gb = gt[(size_t)b * MBOX + j];
  float gar = (gb.z - gb.x) * (gb.w - gb.y);
  u64 t[8] = {0, 0, 0, 0, 0, 0, 0, 0};
  for (int k = 0; k < 64; ++k) {
    int r = (k << 6) + lane;  // coalesced
    float4 a = prb[r];
    float areaA = (a.z - a.x) * (a.w - a.y);
    u64 key = ((u64)iou_bits(a, areaA, gb, gar) << 13) | (u64)(NBOX - r);
    if (key > t[7]) {
      t[7] = key;
      #pragma unroll
      for (int q = 7; q > 0; --q)
        if (t[q] > t[q - 1]) { u64 tmp = t[q]; t[q] = t[q - 1]; t[q - 1] = tmp; }
    }
  }
  u64* out = top8G + ((size_t)b * MBOX + j) * 8;
  int h = 0;
  for (int e = 0; e < 8; ++e) {
    u64 cand = 0;
    #pragma unroll
    for (int q = 0; q < 8; ++q) if (q == h) cand = t[q];  // static reg index
    u64 m = cand;
    #pragma unroll
    for (int o = 32; o; o >>= 1) {
      u64 q2 = shflxor_u64(m, o);
      if (q2 > m) m = q2;
    }
    if (cand == m && m) h++;  // unique winner (keys distinct)
    if (lane == 0) out[e] = m;
  }
}

__global__ __launch_bounds__(MT) void match_kernel(
    const float4* __restrict__ pr, const float4* __restrict__ gt,
    const u16* __restrict__ rowcolG, const u64* __restrict__ top8G,
    const float* __restrict__ negpart, float* __restrict__ partial) {
  __shared__ u16 rowcol[NBOX];      // argmax col per live row; 0xFFFF = matched
  __shared__ u64 top8[MBOX][8];
  __shared__ float4 g[MBOX];
  __shared__ float garea[MBOX];
  __shared__ unsigned char colact[MBOX];
  __shared__ u16 wl[MW][256];
  __shared__ u16 colwl[MBOX];
  __shared__ int wlcnt[MW];
  __shared__ int colcnt2[2];        // parity-indexed: P1(t+1) writes while P3b(t) reads other slot
  __shared__ int nmatch;
  __shared__ float redA[MW], redB[MW];

  const int b = blockIdx.x, tid = threadIdx.x;
  const int lane = tid & 63, wid = tid >> 6;
  const float4* prb = pr + (size_t)b * NBOX;

  for (int k = tid; k < NBOX; k += MT) rowcol[k] = rowcolG[(size_t)b * NBOX + k];
  for (int k = tid; k < MBOX * 8; k += MT) (&top8[0][0])[k] = top8G[(size_t)b * MBOX * 8 + k];
  if (tid < MBOX) {
    float4 gg = gt[(size_t)b * MBOX + tid];
    g[tid] = gg;
    garea[tid] = (gg.z - gg.x) * (gg.w - gg.y);
    colact[tid] = 1;
  }
  if (tid == 0) { nmatch = 0; colcnt2[0] = 0; colcnt2[1] = 0; }
  if (lane == 0) wlcnt[wid] = 0;
  __syncthreads();

  float possum = 0.0f, negsub = 0.0f;

  for (int round = 0; round < ROUND_CAP; ++round) {
    // P1: per active col, head-of-list (first live entry) + mutual-best test
    if (tid < MBOX && colact[tid]) {
      const int j = tid;
      u64 ev[8]; int rw[8]; u16 rcv[8];
      #pragma unroll
      for (int q = 0; q < 8; ++q) ev[q] = top8[j][q];
      #pragma unroll
      for (int q = 0; q < 8; ++q) {
        rw[q] = NBOX - (int)(ev[q] & 0x1FFFull);
        rcv[q] = rowcol[rw[q]];
      }
      int rsel = -1; u16 rcsel = 0;
      #pragma unroll
      for (int q = 7; q >= 0; --q)
        if (rcv[q] != 0xFFFFu) { rsel = rw[q]; rcsel = rcv[q]; }  // ends at first live
      if (rsel < 0) {
        int x = atomicAdd(&colcnt2[round & 1], 1);  // list exhausted -> rebuild
        colwl[x] = (u16)j;
      } else if ((int)rcsel == j) {                 // mutual best -> greedy-safe match
        colact[j] = 0;
        rowcol[rsel] = 0xFFFFu;
        float4 a = prb[rsel];
        float4 gg = g[j];
        possum += giou_loss(a.x, a.y, a.z, a.w, gg.x, gg.y, gg.z, gg.w);
        negsub += giou_loss(a.x, a.y, a.z, a.w, 0.0f, 0.0f, 0.0f, 0.0f);
        atomicAdd(&nmatch, 1);
      }
    }
    __syncthreads();  // B1
    if (nmatch >= MBOX) break;
    if (tid == 0) colcnt2[(round + 1) & 1] = 0;  // reset other-parity slot for next P1

    // P2: rows whose argmax col died -> per-wave worklist (rows partitioned by owner thread)
    #pragma unroll
    for (int k = 0; k < NBOX / MT; ++k) {
      int r = tid + k * MT;
      u16 rc = rowcol[r];
      if (rc != 0xFFFFu && !colact[rc]) {
        int x = atomicAdd(&wlcnt[wid], 1);
        wl[wid][x] = (u16)r;
      }
    }
    // P3a: wave recomputes its own rows, 4 at a time (16 lanes x 16 cols)
    int rcnt = wlcnt[wid];
    if (lane == 0) wlcnt[wid] = 0;  // same-wave order: all lanes read rcnt first
    for (int base = 0; base < rcnt; base += 4) {
      int idx = base + (lane >> 4);
      bool act = idx < rcnt;
      int r = act ? (int)wl[wid][idx] : 0;
      float4 a = prb[r];
      float areaA = (a.z - a.x) * (a.w - a.y);
      int cl = lane & 15;
      u64 best = 0ull;
      #pragma unroll
      for (int t2 = 0; t2 < 16; ++t2) {
        int c = cl + (t2 << 4);
        if (colact[c]) {
          u64 p = ((u64)iou_bits(a, areaA, g[c], garea[c]) << 9) | (u64)(MBOX - c);
          if (p > best) best = p;
        }
      }
      #pragma unroll
      for (int o = 8; o; o >>= 1) {
        u64 q2 = shflxor_u64(best, o);
        if (q2 > best) best = q2;
      }
      if (act && cl == 0) rowcol[r] = (u16)(MBOX - (int)(best & 0x1FFull));
    }
    // P3b: rare top-8 rebuilds (wave per col; liveness via rowcol != 0xFFFF)
    int ccnt = colcnt2[round & 1];
    for (int x = wid; x < ccnt; x += MW) {
      int j = (int)colwl[x];
      float4 gb = g[j];
      float gar = garea[j];
      u64 t[8] = {0, 0, 0, 0, 0, 0, 0, 0};
      for (int k = 0; k < NBOX / 64; ++k) {
        int r = (k << 6) + lane;
        if (rowcol[r] != 0xFFFFu) {  // concurrent P3a writes keep liveness unchanged
          float4 a = prb[r];
          float areaA = (a.z - a.x) * (a.w - a.y);
          u64 key = ((u64)iou_bits(a, areaA, gb, gar) << 13) | (u64)(NBOX - r);
          if (key > t[7]) {
            t[7] = key;
            #pragma unroll
            for (int q = 7; q > 0; --q)
              if (t[q] > t[q - 1]) { u64 tmp = t[q]; t[q] = t[q - 1]; t[q - 1] = tmp; }
          }
        }
      }
      int h = 0;
      for (int e = 0; e < 8; ++e) {
        u64 cand = 0;
        #pragma unroll
        for (int q = 0; q < 8; ++q) if (q == h) cand = t[q];
        u64 m = cand;
        #pragma unroll
        for (int o = 32; o; o >>= 1) {
          u64 q2 = shflxor_u64(m, o);
          if (q2 > m) m = q2;
        }
        if (cand == m && m) h++;
        if (lane == 0) top8[j][e] = m;
      }
    }
    __syncthreads();  // B2
  }

  // final reduce: possum/256 + (negG - negsub)/3840
  #pragma unroll
  for (int o = 32; o; o >>= 1) {
    possum += __shfl_xor(possum, o, 64);
    negsub += __shfl_xor(negsub, o, 64);
  }
  if (lane == 0) { redA[wid] = possum; redB[wid] = negsub; }
  __syncthreads();
  if (tid == 0) {
    float pa = 0.0f, ns = 0.0f;
    for (int w = 0; w < MW; ++w) { pa += redA[w]; ns += redB[w]; }
    float ng = 0.0f;
    for (int s = 0; s < ISLICES; ++s) ng += negpart[b * ISLICES + s];
    partial[b] = pa / 256.0f + (ng - ns) / 3840.0f;
  }
}

__global__ void finalize_kernel(const float* __restrict__ partial, float* __restrict__ out) {
  if (threadIdx.x == 0) {
    float s = 0.0f;
    for (int i = 0; i < NBATCH; ++i) s += partial[i];
    out[0] = s / 64.0f;  // /count(=32)/2
  }
}

extern "C" void kernel_launch(void* const* d_in, const int* in_sizes, int n_in,
                              void* d_out, int out_size, void* d_ws, size_t ws_size,
                              hipStream_t stream) {
  (void)in_sizes; (void)n_in; (void)out_size; (void)ws_size;
  const float4* pr = (const float4*)d_in[0];
  const float4* gt = (const float4*)d_in[1];
  char* ws = (char*)d_ws;
  u16* rowcolG = (u16*)(ws + WS_ROWCOL);
  u64* top8G = (u64*)(ws + WS_TOP8);
  float* negpart = (float*)(ws + WS_NEGP);
  float* partial = (float*)(ws + WS_PART);
  float* out = (float*)d_out;

  hipLaunchKernelGGL(init_rows, dim3(NBATCH * ISLICES), dim3(1024), 0, stream,
                     pr, gt, rowcolG, negpart);
  hipLaunchKernelGGL(init_cols, dim3(NBATCH * 64), dim3(256), 0, stream,
                     pr, gt, top8G);
  hipLaunchKernelGGL(match_kernel, dim3(NBATCH), dim3(MT), 0, stream,
                     pr, gt, rowcolG, top8G, negpart, partial);
  hipLaunchKernelGGL(finalize_kernel, dim3(1), dim3(64), 0, stream, partial, out);
}